// Round 13
// baseline (84.649 us; speedup 1.0000x reference)
//
#include <hip/hip_runtime.h>
#include <hip/hip_bf16.h>

#define DD 384
#define NB 2048
#define NA 64
#define NN (NB*NA)

using bhalf8 = __attribute__((ext_vector_type(8))) __bf16;
using f32x4  = __attribute__((ext_vector_type(4))) float;
typedef unsigned short u16;
typedef unsigned char u8;

#define AS1 __attribute__((address_space(1)))
#define AS3 __attribute__((address_space(3)))

__device__ __forceinline__ void gl_lds16(const void* g, void* l) {
  __builtin_amdgcn_global_load_lds((const AS1 void*)g, (AS3 void*)l, 16, 0, 0);
}

__device__ __forceinline__ u16 f2b(float f) {
  __hip_bfloat16 h = __float2bfloat16(f);
  union { __hip_bfloat16 h; u16 u; } c; c.h = h; return c.u;
}
__device__ __forceinline__ float b2f(u16 u) {
  union { unsigned int i; float f; } c; c.i = ((unsigned int)u) << 16; return c.f;
}
__device__ __forceinline__ float celu_f(float v) {
  return v > 0.f ? v : 0.1f * (__expf(v * 10.f) - 1.f);
}
__device__ __forceinline__ bhalf8 pack8(float4 a, float4 b) {
  union { u16 us[8]; bhalf8 v; } t;
  t.us[0]=f2b(a.x); t.us[1]=f2b(a.y); t.us[2]=f2b(a.z); t.us[3]=f2b(a.w);
  t.us[4]=f2b(b.x); t.us[5]=f2b(b.y); t.us[6]=f2b(b.z); t.us[7]=f2b(b.w);
  return t.v;
}

// ---------------- prep: fused species-scatter + energy-zero + weight images ----------------

__global__ void k_prep(const int* __restrict__ species, int* __restrict__ cursors,
                       float* __restrict__ out, int* __restrict__ sorted,
                       const float* __restrict__ W0, const float* __restrict__ W1,
                       const float* __restrict__ W2, const float* __restrict__ W3,
                       u16* __restrict__ W0img, u16* __restrict__ W1img,
                       u16* __restrict__ W2img, u16* __restrict__ W3B) {
  int tid = threadIdx.x;
  int id = blockIdx.x * 256 + tid;
  if (blockIdx.x < 512) {
    __shared__ int lcnt[4];
    __shared__ int lbase[4];
    if (tid < 4) lcnt[tid] = 0;
    __syncthreads();
    int s = species[id];
    out[id] = (float)s;
    int lpos = atomicAdd(&lcnt[s], 1);
    __syncthreads();
    if (tid < 4) lbase[tid] = atomicAdd(&cursors[tid], lcnt[tid]);
    __syncthreads();
    sorted[s * NN + lbase[s] + lpos] = id;
  } else if (blockIdx.x < 520) {
    out[NN + (blockIdx.x - 512) * 256 + tid] = 0.f;
  }
  if (id < 245760) {
    int t = id / 61440, r1 = id % 61440;
    int kc = r1 / 5120, r2 = r1 % 5120;
    int r = r2 >> 5, rem = r2 & 31, s = rem >> 3, e = rem & 7;
    int k = kc * 32 + (s ^ ((r >> 1) & 3)) * 8 + e;
    W0img[id] = f2b(W0[t * 61440 + k * 160 + r]);
  } else if ((id -= 245760) < 81920) {
    int t = id / 20480, r1 = id % 20480;
    int kc = r1 / 4096, r2 = r1 % 4096;
    int r = r2 >> 5, rem = r2 & 31, s = rem >> 3, e = rem & 7;
    int k = kc * 32 + (s ^ ((r >> 1) & 3)) * 8 + e;
    W1img[id] = f2b(W1[t * 20480 + k * 128 + r]);
  } else if ((id -= 81920) < 65536) {
    int t = id / 16384, r1 = id % 16384;
    int kc = r1 / 4096, r2 = r1 % 4096;
    int r = r2 >> 5, rem = r2 & 31, s = rem >> 3, e = rem & 7;
    u16 v = 0;
    if (r < 96) {
      int k = kc * 32 + (s ^ ((r >> 1) & 3)) * 8 + e;
      v = f2b(W2[t * 12288 + k * 96 + r]);
    }
    W2img[id] = v;
  } else if ((id -= 65536) < 384) {
    W3B[id] = f2b(W3[id]);
  }
}

// ---------------- fused MFMA MLP ----------------
// LDS 32768 B -> 5 blocks/CU. 1-D grid (2051 blocks), on-device (type,tile).
// L0: 12 single-barrier phases, 4 A-buffers, 3 chunks staged ahead.
// vmcnt constants are TAIL-ANCHORED (robust to VMEM issue reordering of the
// plain bf loads across the LDS-DMA intrinsics — the r12 bug):
//   need A(kc) drained at phase-kc top; A(kc)'s last op always has >= N ops
//   issued after it, N = {ph0: 7 (A1,A2 + worst-case bf0 before A0 -> use 4),
//   ph1: 7 (body0), ph2-9: 14 (bodies kc-2,kc-1), ph10: 12, ph11: 10}.
//   DMA intrinsics are mutually ordered; only pure loads float.
// L1/L2: barrier-free bodies. L3: atomicAdd energies into out[NN+mol].

__global__ __launch_bounds__(256, 5) void k_mlp(
    const float* __restrict__ aev, const int* __restrict__ sorted,
    const int* __restrict__ counts,
    const u16* __restrict__ W0img, const u16* __restrict__ W1img,
    const u16* __restrict__ W2img, const u16* __restrict__ W3B,
    const float* __restrict__ b0, const float* __restrict__ b1,
    const float* __restrict__ b2, const float* __restrict__ b3,
    float* __restrict__ outE)
{
  int c0 = counts[0], c1 = counts[1], c2 = counts[2], c3 = counts[3];
  int T0 = (c0 + 63) >> 6, T1 = (c1 + 63) >> 6, T2 = (c2 + 63) >> 6;
  int b = blockIdx.x, type, tile;
  if (b < T0)              { type = 0; tile = b; }
  else if ((b -= T0) < T1) { type = 1; tile = b; }
  else if ((b -= T1) < T2) { type = 2; tile = b; }
  else { type = 3; tile = b - T2; }
  int cnt = (type == 0) ? c0 : (type == 1) ? c1 : (type == 2) ? c2 : c3;
  if (tile * 64 >= cnt) return;

  __shared__ uint4 smem4[2048];            // 32768 B
  u8* smem = (u8*)smem4;
  u8*  Ast = smem;                         // [4][8192]
  u16* sH0 = (u16*)smem;                   // [64][168]
  u16* sH1 = (u16*)smem;                   // [64][136]
  u16* sH2 = (u16*)smem;                   // [64][104]

  int tid = threadIdx.x, lane = tid & 63, w = tid >> 6;
  int wm = w & 1, wn = w >> 1, l15 = lane & 15, lk = lane >> 4;
  int base = type * NN + tile * 64, nvalid = min(64, cnt - tile * 64);

  // ---- A staging sources ----
  int arow0 = w * 16 + (lane >> 3), arow1 = arow0 + 8;
  const float* a0 = aev + (size_t)sorted[base + min(arow0, nvalid - 1)] * DD
                    + (((lane & 7) ^ (arow0 & 7)) << 2);
  const float* a1 = aev + (size_t)sorted[base + min(arow1, nvalid - 1)] * DD
                    + (((lane & 7) ^ (arow1 & 7)) << 2);
  u8* dA = Ast + w * 2048;

#define STG_A(KC, B_) do { \
    gl_lds16(a0 + (KC) * 32, dA + (B_) * 8192); \
    gl_lds16(a1 + (KC) * 32, dA + (B_) * 8192 + 1024); \
  } while (0)

  // ---- fragment offsets ----
  int bsw = (lk ^ ((l15 >> 1) & 3)) << 4;
  const u8* gB0 = (const u8*)W0img + (size_t)type * 122880 + ((wn * 80 + l15) << 6) + bsw;
  int aoff0 = (wm * 32 + l15) * 128, aoff1 = aoff0 + 2048;
  int sAa = (((2 * lk)     ^ (l15 & 7)) << 4);
  int sAb = (((2 * lk + 1) ^ (l15 & 7)) << 4);

#define TOPW(WN) do { \
  asm volatile("s_waitcnt vmcnt(" #WN ")" ::: "memory"); \
  __builtin_amdgcn_sched_barrier(0); \
  __builtin_amdgcn_s_barrier(); \
  __builtin_amdgcn_sched_barrier(0); } while (0)
#define TAILW() do { \
  asm volatile("s_waitcnt lgkmcnt(0)" ::: "memory"); \
  __builtin_amdgcn_sched_barrier(0); \
  __builtin_amdgcn_s_barrier(); \
  __builtin_amdgcn_sched_barrier(0); } while (0)

  // ---------- Layer 0: 12 single-barrier phases, 3-ahead ----------
  f32x4 acc0[2][5];
  #pragma unroll
  for (int mt = 0; mt < 2; ++mt)
    #pragma unroll
    for (int nt = 0; nt < 5; ++nt) acc0[mt][nt] = f32x4{0.f, 0.f, 0.f, 0.f};

  bhalf8 bf[5];
  STG_A(0, 0);
  #pragma unroll
  for (int nt = 0; nt < 5; ++nt) bf[nt] = *(const bhalf8*)(gB0 + nt * 1024);
  STG_A(1, 1);
  STG_A(2, 2);

#define PHA(KC, WN) \
  TOPW(WN); \
  { const u8* bA = Ast + ((KC) % 4) * 8192; \
    bhalf8 af0 = pack8(*(const float4*)(bA + aoff0 + sAa), *(const float4*)(bA + aoff0 + sAb)); \
    bhalf8 af1 = pack8(*(const float4*)(bA + aoff1 + sAa), *(const float4*)(bA + aoff1 + sAb)); \
    _Pragma("unroll") \
    for (int nt = 0; nt < 5; ++nt) { \
      acc0[0][nt] = __builtin_amdgcn_mfma_f32_16x16x32_bf16(af0, bf[nt], acc0[0][nt], 0, 0, 0); \
      acc0[1][nt] = __builtin_amdgcn_mfma_f32_16x16x32_bf16(af1, bf[nt], acc0[1][nt], 0, 0, 0); \
    } \
    if ((KC) < 11) { \
      _Pragma("unroll") \
      for (int nt = 0; nt < 5; ++nt) \
        bf[nt] = *(const bhalf8*)(gB0 + ((KC) + 1) * 10240 + nt * 1024); \
    } } \
  if ((KC) < 9) STG_A((KC) + 3, ((KC) + 3) % 4);

  PHA(0, 4)   PHA(1, 7)   PHA(2, 14)  PHA(3, 14)  PHA(4, 14)  PHA(5, 14)
  PHA(6, 14)  PHA(7, 14)  PHA(8, 14)  PHA(9, 14)  PHA(10, 12) PHA(11, 10)
#undef PHA
#undef STG_A

  TAILW();

  // L0 epilogue -> sH0
  #pragma unroll
  for (int mt = 0; mt < 2; ++mt)
    #pragma unroll
    for (int nt = 0; nt < 5; ++nt) {
      int col = wn * 80 + nt * 16 + l15;
      float bias = b0[type * 160 + col];
      #pragma unroll
      for (int i = 0; i < 4; ++i) {
        int row = wm * 32 + mt * 16 + lk * 4 + i;
        sH0[row * 168 + col] = f2b(celu_f(acc0[mt][nt][i] + bias));
      }
    }
  TAILW();

  // ---------- Layer 1: barrier-free body ----------
  const u8* gW1 = (const u8*)W1img + (size_t)type * 40960 + ((wn * 64 + l15) << 6) + bsw;
  f32x4 acc1[2][4];
  #pragma unroll
  for (int mt = 0; mt < 2; ++mt)
    #pragma unroll
    for (int nt = 0; nt < 4; ++nt) acc1[mt][nt] = f32x4{0.f, 0.f, 0.f, 0.f};

  #pragma unroll
  for (int kc = 0; kc < 5; ++kc) {
    bhalf8 af0 = *(const bhalf8*)&sH0[(wm * 32 + l15) * 168 + kc * 32 + lk * 8];
    bhalf8 af1 = *(const bhalf8*)&sH0[(wm * 32 + 16 + l15) * 168 + kc * 32 + lk * 8];
    bhalf8 bw[4];
    #pragma unroll
    for (int nt = 0; nt < 4; ++nt)
      bw[nt] = *(const bhalf8*)(gW1 + kc * 8192 + nt * 1024);
    #pragma unroll
    for (int nt = 0; nt < 4; ++nt) {
      acc1[0][nt] = __builtin_amdgcn_mfma_f32_16x16x32_bf16(af0, bw[nt], acc1[0][nt], 0, 0, 0);
      acc1[1][nt] = __builtin_amdgcn_mfma_f32_16x16x32_bf16(af1, bw[nt], acc1[1][nt], 0, 0, 0);
    }
  }
  TAILW();

  #pragma unroll
  for (int mt = 0; mt < 2; ++mt)
    #pragma unroll
    for (int nt = 0; nt < 4; ++nt) {
      int col = wn * 64 + nt * 16 + l15;
      float bias = b1[type * 128 + col];
      #pragma unroll
      for (int i = 0; i < 4; ++i) {
        int row = wm * 32 + mt * 16 + lk * 4 + i;
        sH1[row * 136 + col] = f2b(celu_f(acc1[mt][nt][i] + bias));
      }
    }
  TAILW();

  // ---------- Layer 2: barrier-free body ----------
  const u8* gW2 = (const u8*)W2img + (size_t)type * 32768 + ((wn * 48 + l15) << 6) + bsw;
  f32x4 acc2[2][3];
  #pragma unroll
  for (int mt = 0; mt < 2; ++mt)
    #pragma unroll
    for (int nt = 0; nt < 3; ++nt) acc2[mt][nt] = f32x4{0.f, 0.f, 0.f, 0.f};

  #pragma unroll
  for (int kc = 0; kc < 4; ++kc) {
    bhalf8 af0 = *(const bhalf8*)&sH1[(wm * 32 + l15) * 136 + kc * 32 + lk * 8];
    bhalf8 af1 = *(const bhalf8*)&sH1[(wm * 32 + 16 + l15) * 136 + kc * 32 + lk * 8];
    bhalf8 bw[3];
    #pragma unroll
    for (int nt = 0; nt < 3; ++nt)
      bw[nt] = *(const bhalf8*)(gW2 + kc * 8192 + nt * 1024);
    #pragma unroll
    for (int nt = 0; nt < 3; ++nt) {
      acc2[0][nt] = __builtin_amdgcn_mfma_f32_16x16x32_bf16(af0, bw[nt], acc2[0][nt], 0, 0, 0);
      acc2[1][nt] = __builtin_amdgcn_mfma_f32_16x16x32_bf16(af1, bw[nt], acc2[1][nt], 0, 0, 0);
    }
  }
  TAILW();

  #pragma unroll
  for (int mt = 0; mt < 2; ++mt)
    #pragma unroll
    for (int nt = 0; nt < 3; ++nt) {
      int col = wn * 48 + nt * 16 + l15;
      float bias = b2[type * 96 + col];
      #pragma unroll
      for (int i = 0; i < 4; ++i) {
        int row = wm * 32 + mt * 16 + lk * 4 + i;
        sH2[row * 104 + col] = f2b(celu_f(acc2[mt][nt][i] + bias));
      }
    }
  TAILW();

  // ---------- Layer 3: [64 x 96] @ [96 x 1] -> molecule energy atomicAdd ----------
  {
    int atom = tid >> 2;
    int q = tid & 3;
    const u16* w3 = W3B + type * 96 + q * 24;
    const u16* hrow = sH2 + atom * 104 + q * 24;
    float s = 0.f;
    #pragma unroll
    for (int i = 0; i < 3; ++i) {
      union { bhalf8 v; u16 u[8]; } hu, wu2;
      hu.v = *(const bhalf8*)&hrow[i * 8];
      wu2.v = *(const bhalf8*)&w3[i * 8];
      #pragma unroll
      for (int j = 0; j < 8; ++j)
        s += b2f(hu.u[j]) * b2f(wu2.u[j]);
    }
    s += __shfl_xor(s, 1);
    s += __shfl_xor(s, 2);
    if (q == 0 && atom < nvalid) {
      int ai = sorted[base + atom];
      atomicAdd(&outE[ai >> 6], s + b3[type]);
    }
  }
}

// ---------------- launch ----------------

extern "C" void kernel_launch(void* const* d_in, const int* in_sizes, int n_in,
                              void* d_out, int out_size, void* d_ws, size_t ws_size,
                              hipStream_t stream) {
  const int*   species = (const int*)d_in[0];
  const float* aev = (const float*)d_in[1];
  const float* W0 = (const float*)d_in[2];
  const float* b0 = (const float*)d_in[3];
  const float* W1 = (const float*)d_in[4];
  const float* b1 = (const float*)d_in[5];
  const float* W2 = (const float*)d_in[6];
  const float* b2 = (const float*)d_in[7];
  const float* W3 = (const float*)d_in[8];
  const float* b3 = (const float*)d_in[9];
  float* out = (float*)d_out;

  unsigned char* ws = (unsigned char*)d_ws;
  int* cursors = (int*)(ws + 0);                // [4] bin cursors == counts after k_prep
  int* sorted = (int*)(ws + 64);                // int[4*NN] (4 disjoint bins)
  u16* W0img = (u16*)(ws + 2097216);            // 245760 u16
  u16* W1img = (u16*)(ws + 2588736);            // 81920 u16
  u16* W2img = (u16*)(ws + 2752576);            // 65536 u16
  u16* W3B   = (u16*)(ws + 2883648);            // 384 u16

  hipMemsetAsync(cursors, 0, 16, stream);
  k_prep<<<1538, 256, 0, stream>>>(species, cursors, out, sorted,
        W0, W1, W2, W3, W0img, W1img, W2img, W3B);
  k_mlp<<<2051, 256, 0, stream>>>(aev, sorted, cursors,
        W0img, W1img, W2img, W3B, b0, b1, b2, b3, out + NN);
}

// Round 14
// 71.011 us; speedup vs baseline: 1.1921x; 1.1921x over previous
//
#include <hip/hip_runtime.h>
#include <hip/hip_bf16.h>

#define DD 384
#define NB 2048
#define NA 64
#define NN (NB*NA)

using bhalf8 = __attribute__((ext_vector_type(8))) __bf16;
using f32x4  = __attribute__((ext_vector_type(4))) float;
typedef unsigned short u16;
typedef unsigned char u8;

#define AS1 __attribute__((address_space(1)))
#define AS3 __attribute__((address_space(3)))

__device__ __forceinline__ void gl_lds16(const void* g, void* l) {
  __builtin_amdgcn_global_load_lds((const AS1 void*)g, (AS3 void*)l, 16, 0, 0);
}

__device__ __forceinline__ u16 f2b(float f) {
  __hip_bfloat16 h = __float2bfloat16(f);
  union { __hip_bfloat16 h; u16 u; } c; c.h = h; return c.u;
}
__device__ __forceinline__ float b2f(u16 u) {
  union { unsigned int i; float f; } c; c.i = ((unsigned int)u) << 16; return c.f;
}
__device__ __forceinline__ float celu_f(float v) {
  return v > 0.f ? v : 0.1f * (__expf(v * 10.f) - 1.f);
}
__device__ __forceinline__ bhalf8 pack8(float4 a, float4 b) {
  union { u16 us[8]; bhalf8 v; } t;
  t.us[0]=f2b(a.x); t.us[1]=f2b(a.y); t.us[2]=f2b(a.z); t.us[3]=f2b(a.w);
  t.us[4]=f2b(b.x); t.us[5]=f2b(b.y); t.us[6]=f2b(b.z); t.us[7]=f2b(b.w);
  return t.v;
}

// ---------------- prep: fused species-scatter + weight images ----------------
// Species blocks (0..511): species floats to out, bin atoms into 4 disjoint
// regions sorted[s*NN + pos] (atomicAdd-ticketed). cursors[t] -> count[t].
// Image (W0/W1/W2): per K=32 chunk: [R rows][4 slots][8 bf16], slot s holds
// k-slot j = s ^ ((r>>1)&3); 1 KB contiguous per (wave,nt) fragment.
// W0img: [t][12 kc][160 r]; W1img: [t][5 kc][128 r]; W2img: [t][4 kc][128 r, 96+ zero]

__global__ void k_prep(const int* __restrict__ species, int* __restrict__ cursors,
                       float* __restrict__ out_sp, int* __restrict__ sorted,
                       const float* __restrict__ W0, const float* __restrict__ W1,
                       const float* __restrict__ W2, const float* __restrict__ W3,
                       u16* __restrict__ W0img, u16* __restrict__ W1img,
                       u16* __restrict__ W2img, u16* __restrict__ W3B) {
  int tid = threadIdx.x;
  int id = blockIdx.x * 256 + tid;
  if (blockIdx.x < 512) {
    __shared__ int lcnt[4];
    __shared__ int lbase[4];
    if (tid < 4) lcnt[tid] = 0;
    __syncthreads();
    int s = species[id];
    out_sp[id] = (float)s;
    int lpos = atomicAdd(&lcnt[s], 1);
    __syncthreads();
    if (tid < 4) lbase[tid] = atomicAdd(&cursors[tid], lcnt[tid]);
    __syncthreads();
    sorted[s * NN + lbase[s] + lpos] = id;
  }
  if (id < 245760) {
    int t = id / 61440, r1 = id % 61440;
    int kc = r1 / 5120, r2 = r1 % 5120;
    int r = r2 >> 5, rem = r2 & 31, s = rem >> 3, e = rem & 7;
    int k = kc * 32 + (s ^ ((r >> 1) & 3)) * 8 + e;
    W0img[id] = f2b(W0[t * 61440 + k * 160 + r]);
  } else if ((id -= 245760) < 81920) {
    int t = id / 20480, r1 = id % 20480;
    int kc = r1 / 4096, r2 = r1 % 4096;
    int r = r2 >> 5, rem = r2 & 31, s = rem >> 3, e = rem & 7;
    int k = kc * 32 + (s ^ ((r >> 1) & 3)) * 8 + e;
    W1img[id] = f2b(W1[t * 20480 + k * 128 + r]);
  } else if ((id -= 81920) < 65536) {
    int t = id / 16384, r1 = id % 16384;
    int kc = r1 / 4096, r2 = r1 % 4096;
    int r = r2 >> 5, rem = r2 & 31, s = rem >> 3, e = rem & 7;
    u16 v = 0;
    if (r < 96) {
      int k = kc * 32 + (s ^ ((r >> 1) & 3)) * 8 + e;
      v = f2b(W2[t * 12288 + k * 96 + r]);
    }
    W2img[id] = v;
  } else if ((id -= 65536) < 384) {
    W3B[id] = f2b(W3[id]);
  }
}

// ---------------- fused MFMA MLP (r11 structure + 1-D grid + setprio) ----------------
// LDS 24576 B: Ast [0,24576) = 3 x 8192-B fp32 A-chunk buffers (L0 only);
// sH0 [0,21504) u16[64][168] overlays after L0; sH1 [0,17408); sH2 [0,13312).
// L0: 12 single-barrier phases, 3-deep A buffers (2 chunks ahead), vmcnt(2)
// tail-anchored (drain all but 2 newest -> A(kc) always retired regardless of
// VMEM issue reorder). B fragments: direct global->VGPR (1 KB coalesced,
// L2-resident), prefetched one phase ahead. L1/L2: barrier-free bodies.
// T5: s_setprio(1) around MFMA clusters (5 independent blocks/CU regime).

__global__ __launch_bounds__(256, 5) void k_mlp(
    const float* __restrict__ aev, const int* __restrict__ sorted,
    const int* __restrict__ counts,
    const u16* __restrict__ W0img, const u16* __restrict__ W1img,
    const u16* __restrict__ W2img, const u16* __restrict__ W3B,
    const float* __restrict__ b0, const float* __restrict__ b1,
    const float* __restrict__ b2, const float* __restrict__ b3,
    float* __restrict__ atom_out)
{
  int c0 = counts[0], c1 = counts[1], c2 = counts[2], c3 = counts[3];
  int T0 = (c0 + 63) >> 6, T1 = (c1 + 63) >> 6, T2 = (c2 + 63) >> 6;
  int b = blockIdx.x, type, tile;
  if (b < T0)              { type = 0; tile = b; }
  else if ((b -= T0) < T1) { type = 1; tile = b; }
  else if ((b -= T1) < T2) { type = 2; tile = b; }
  else { type = 3; tile = b - T2; }
  int cnt = (type == 0) ? c0 : (type == 1) ? c1 : (type == 2) ? c2 : c3;
  if (tile * 64 >= cnt) return;

  __shared__ uint4 smem4[1536];            // 24576 B
  u8* smem = (u8*)smem4;
  u8*  Ast = smem;                         // [3][8192]
  u16* sH0 = (u16*)smem;                   // [64][168]
  u16* sH1 = (u16*)smem;                   // [64][136]
  u16* sH2 = (u16*)smem;                   // [64][104]

  int tid = threadIdx.x, lane = tid & 63, w = tid >> 6;
  int wm = w & 1, wn = w >> 1, l15 = lane & 15, lk = lane >> 4;
  int base = type * NN + tile * 64, nvalid = min(64, cnt - tile * 64);

  // ---- A staging sources (wave w stages rows w*16..w*16+16, inverse-swizzled src) ----
  int arow0 = w * 16 + (lane >> 3), arow1 = arow0 + 8;
  const float* a0 = aev + (size_t)sorted[base + min(arow0, nvalid - 1)] * DD
                    + (((lane & 7) ^ (arow0 & 7)) << 2);
  const float* a1 = aev + (size_t)sorted[base + min(arow1, nvalid - 1)] * DD
                    + (((lane & 7) ^ (arow1 & 7)) << 2);
  u8* dA = Ast + w * 2048;

#define STG_A(KC, B_) do { \
    gl_lds16(a0 + (KC) * 32, dA + (B_) * 8192); \
    gl_lds16(a1 + (KC) * 32, dA + (B_) * 8192 + 1024); \
  } while (0)

  // ---- fragment offsets ----
  int bsw = (lk ^ ((l15 >> 1) & 3)) << 4;
  const u8* gB0 = (const u8*)W0img + (size_t)type * 122880 + ((wn * 80 + l15) << 6) + bsw;
  int aoff0 = (wm * 32 + l15) * 128, aoff1 = aoff0 + 2048;
  int sAa = (((2 * lk)     ^ (l15 & 7)) << 4);
  int sAb = (((2 * lk + 1) ^ (l15 & 7)) << 4);

#define TOPW(WN) do { \
  asm volatile("s_waitcnt vmcnt(" #WN ")" ::: "memory"); \
  __builtin_amdgcn_sched_barrier(0); \
  __builtin_amdgcn_s_barrier(); \
  __builtin_amdgcn_sched_barrier(0); } while (0)
#define TAILW() do { \
  asm volatile("s_waitcnt lgkmcnt(0)" ::: "memory"); \
  __builtin_amdgcn_sched_barrier(0); \
  __builtin_amdgcn_s_barrier(); \
  __builtin_amdgcn_sched_barrier(0); } while (0)

  // ---------- Layer 0: 12 single-barrier phases ----------
  f32x4 acc0[2][5];
  #pragma unroll
  for (int mt = 0; mt < 2; ++mt)
    #pragma unroll
    for (int nt = 0; nt < 5; ++nt) acc0[mt][nt] = f32x4{0.f, 0.f, 0.f, 0.f};

  bhalf8 bf[5];
  STG_A(0, 0);
  #pragma unroll
  for (int nt = 0; nt < 5; ++nt) bf[nt] = *(const bhalf8*)(gB0 + nt * 1024);
  STG_A(1, 1);
  // vmcnt(2) at each phase top: drains all but the 2 newest ops (the A(kc+1)
  // DMA pair) -> A(kc) and bf(kc) retired under any legal VMEM issue order.

#define PHA(KC, WN) \
  TOPW(WN); \
  { const u8* bA = Ast + ((KC) % 3) * 8192; \
    bhalf8 af0 = pack8(*(const float4*)(bA + aoff0 + sAa), *(const float4*)(bA + aoff0 + sAb)); \
    bhalf8 af1 = pack8(*(const float4*)(bA + aoff1 + sAa), *(const float4*)(bA + aoff1 + sAb)); \
    __builtin_amdgcn_s_setprio(1); \
    _Pragma("unroll") \
    for (int nt = 0; nt < 5; ++nt) { \
      acc0[0][nt] = __builtin_amdgcn_mfma_f32_16x16x32_bf16(af0, bf[nt], acc0[0][nt], 0, 0, 0); \
      acc0[1][nt] = __builtin_amdgcn_mfma_f32_16x16x32_bf16(af1, bf[nt], acc0[1][nt], 0, 0, 0); \
    } \
    __builtin_amdgcn_s_setprio(0); \
    if ((KC) < 11) { \
      _Pragma("unroll") \
      for (int nt = 0; nt < 5; ++nt) \
        bf[nt] = *(const bhalf8*)(gB0 + ((KC) + 1) * 10240 + nt * 1024); \
    } } \
  if ((KC) < 10) STG_A((KC) + 2, ((KC) + 2) % 3);

  PHA(0, 2)  PHA(1, 2)  PHA(2, 2)  PHA(3, 2)  PHA(4, 2)  PHA(5, 2)
  PHA(6, 2)  PHA(7, 2)  PHA(8, 2)  PHA(9, 2)  PHA(10, 2) PHA(11, 0)
#undef PHA
#undef STG_A

  // phase-11 ds_reads consumed by own MFMAs; barrier before sH0 overlay
  TAILW();

  // L0 epilogue -> sH0
  #pragma unroll
  for (int mt = 0; mt < 2; ++mt)
    #pragma unroll
    for (int nt = 0; nt < 5; ++nt) {
      int col = wn * 80 + nt * 16 + l15;
      float bias = b0[type * 160 + col];
      #pragma unroll
      for (int i = 0; i < 4; ++i) {
        int row = wm * 32 + mt * 16 + lk * 4 + i;
        sH0[row * 168 + col] = f2b(celu_f(acc0[mt][nt][i] + bias));
      }
    }
  TAILW();

  // ---------- Layer 1: barrier-free body (A = sH0, B = registers) ----------
  const u8* gW1 = (const u8*)W1img + (size_t)type * 40960 + ((wn * 64 + l15) << 6) + bsw;
  f32x4 acc1[2][4];
  #pragma unroll
  for (int mt = 0; mt < 2; ++mt)
    #pragma unroll
    for (int nt = 0; nt < 4; ++nt) acc1[mt][nt] = f32x4{0.f, 0.f, 0.f, 0.f};

  #pragma unroll
  for (int kc = 0; kc < 5; ++kc) {
    bhalf8 af0 = *(const bhalf8*)&sH0[(wm * 32 + l15) * 168 + kc * 32 + lk * 8];
    bhalf8 af1 = *(const bhalf8*)&sH0[(wm * 32 + 16 + l15) * 168 + kc * 32 + lk * 8];
    bhalf8 bw[4];
    #pragma unroll
    for (int nt = 0; nt < 4; ++nt)
      bw[nt] = *(const bhalf8*)(gW1 + kc * 8192 + nt * 1024);
    __builtin_amdgcn_s_setprio(1);
    #pragma unroll
    for (int nt = 0; nt < 4; ++nt) {
      acc1[0][nt] = __builtin_amdgcn_mfma_f32_16x16x32_bf16(af0, bw[nt], acc1[0][nt], 0, 0, 0);
      acc1[1][nt] = __builtin_amdgcn_mfma_f32_16x16x32_bf16(af1, bw[nt], acc1[1][nt], 0, 0, 0);
    }
    __builtin_amdgcn_s_setprio(0);
  }
  TAILW();   // all sH0 reads done before sH1 overlay writes

  #pragma unroll
  for (int mt = 0; mt < 2; ++mt)
    #pragma unroll
    for (int nt = 0; nt < 4; ++nt) {
      int col = wn * 64 + nt * 16 + l15;
      float bias = b1[type * 128 + col];
      #pragma unroll
      for (int i = 0; i < 4; ++i) {
        int row = wm * 32 + mt * 16 + lk * 4 + i;
        sH1[row * 136 + col] = f2b(celu_f(acc1[mt][nt][i] + bias));
      }
    }
  TAILW();

  // ---------- Layer 2: barrier-free body ----------
  const u8* gW2 = (const u8*)W2img + (size_t)type * 32768 + ((wn * 48 + l15) << 6) + bsw;
  f32x4 acc2[2][3];
  #pragma unroll
  for (int mt = 0; mt < 2; ++mt)
    #pragma unroll
    for (int nt = 0; nt < 3; ++nt) acc2[mt][nt] = f32x4{0.f, 0.f, 0.f, 0.f};

  #pragma unroll
  for (int kc = 0; kc < 4; ++kc) {
    bhalf8 af0 = *(const bhalf8*)&sH1[(wm * 32 + l15) * 136 + kc * 32 + lk * 8];
    bhalf8 af1 = *(const bhalf8*)&sH1[(wm * 32 + 16 + l15) * 136 + kc * 32 + lk * 8];
    bhalf8 bw[3];
    #pragma unroll
    for (int nt = 0; nt < 3; ++nt)
      bw[nt] = *(const bhalf8*)(gW2 + kc * 8192 + nt * 1024);
    __builtin_amdgcn_s_setprio(1);
    #pragma unroll
    for (int nt = 0; nt < 3; ++nt) {
      acc2[0][nt] = __builtin_amdgcn_mfma_f32_16x16x32_bf16(af0, bw[nt], acc2[0][nt], 0, 0, 0);
      acc2[1][nt] = __builtin_amdgcn_mfma_f32_16x16x32_bf16(af1, bw[nt], acc2[1][nt], 0, 0, 0);
    }
    __builtin_amdgcn_s_setprio(0);
  }
  TAILW();   // all sH1 reads done before sH2 overlay writes

  #pragma unroll
  for (int mt = 0; mt < 2; ++mt)
    #pragma unroll
    for (int nt = 0; nt < 3; ++nt) {
      int col = wn * 48 + nt * 16 + l15;
      float bias = b2[type * 96 + col];
      #pragma unroll
      for (int i = 0; i < 4; ++i) {
        int row = wm * 32 + mt * 16 + lk * 4 + i;
        sH2[row * 104 + col] = f2b(celu_f(acc2[mt][nt][i] + bias));
      }
    }
  TAILW();

  // ---------- Layer 3: [64 x 96] @ [96 x 1] -> atom_out ----------
  {
    int atom = tid >> 2;
    int q = tid & 3;
    const u16* w3 = W3B + type * 96 + q * 24;
    const u16* hrow = sH2 + atom * 104 + q * 24;
    float s = 0.f;
    #pragma unroll
    for (int i = 0; i < 3; ++i) {
      union { bhalf8 v; u16 u[8]; } hu, wu2;
      hu.v = *(const bhalf8*)&hrow[i * 8];
      wu2.v = *(const bhalf8*)&w3[i * 8];
      #pragma unroll
      for (int j = 0; j < 8; ++j)
        s += b2f(hu.u[j]) * b2f(wu2.u[j]);
    }
    s += __shfl_xor(s, 1);
    s += __shfl_xor(s, 2);
    if (q == 0 && atom < nvalid)
      atom_out[sorted[base + atom]] = s + b3[type];
  }
}

__global__ void k_reduce(const float* __restrict__ atom_out, float* __restrict__ out_e) {
  int mol = blockIdx.x;
  int lane = threadIdx.x;
  float v = atom_out[mol * 64 + lane];
  #pragma unroll
  for (int m = 32; m >= 1; m >>= 1) v += __shfl_xor(v, m);
  if (lane == 0) out_e[mol] = v;
}

// ---------------- launch ----------------

extern "C" void kernel_launch(void* const* d_in, const int* in_sizes, int n_in,
                              void* d_out, int out_size, void* d_ws, size_t ws_size,
                              hipStream_t stream) {
  const int*   species = (const int*)d_in[0];
  const float* aev = (const float*)d_in[1];
  const float* W0 = (const float*)d_in[2];
  const float* b0 = (const float*)d_in[3];
  const float* W1 = (const float*)d_in[4];
  const float* b1 = (const float*)d_in[5];
  const float* W2 = (const float*)d_in[6];
  const float* b2 = (const float*)d_in[7];
  const float* W3 = (const float*)d_in[8];
  const float* b3 = (const float*)d_in[9];
  float* out = (float*)d_out;

  unsigned char* ws = (unsigned char*)d_ws;
  int* cursors = (int*)(ws + 0);                // [4] bin cursors == counts after k_prep
  int* sorted = (int*)(ws + 64);                // int[4*NN] (4 disjoint bins)
  float* atom_out = (float*)(ws + 2097216);     // float[NN]
  u16* W0img = (u16*)(ws + 2621504);            // 245760 u16
  u16* W1img = (u16*)(ws + 3113024);            // 81920 u16
  u16* W2img = (u16*)(ws + 3276864);            // 65536 u16
  u16* W3B   = (u16*)(ws + 3407936);            // 384 u16

  hipMemsetAsync(cursors, 0, 16, stream);
  k_prep<<<1538, 256, 0, stream>>>(species, cursors, out, sorted,
        W0, W1, W2, W3, W0img, W1img, W2img, W3B);
  k_mlp<<<2052, 256, 0, stream>>>(aev, sorted, cursors,
        W0img, W1img, W2img, W3B, b0, b1, b2, b3, atom_out);
  k_reduce<<<NB, 64, 0, stream>>>(atom_out, out + NN);
}